// Round 7
// baseline (339.028 us; speedup 1.0000x reference)
//
#include <hip/hip_runtime.h>

// DIAGNOSTIC ROUND: identical math to R5, but the whole body runs TWICE
// (idempotent — second rep stores the same values). Purpose: make our kernel
// the longest dispatch so rocprof's top-5 finally shows OUR counters
// (VALUBusy / Occupancy / VGPR / LDS conflicts / WRITE_SIZE).
// Perf this round is deliberately sacrificed (~2x kernel time).

#define FDIM 16
#define OUT_PER_ROW 273
#define ROWS_PER_BLOCK 64
#define ROW_STRIDE 17                                  // 16 x-values + 1.0f slot
#define SUPER_FLOATS (ROWS_PER_BLOCK * OUT_PER_ROW)    // 17472
#define SUPER_VEC4   (SUPER_FLOATS / 4)                // 4368 = 17*256 + 16
#define X_VEC4       (ROWS_PER_BLOCK * FDIM / 4)       // 256

typedef float fvec4 __attribute__((ext_vector_type(4)));

__global__ __launch_bounds__(256) void based_feature_kernel(
    const float* __restrict__ x, float* __restrict__ out)
{
    constexpr float C2 = 0.17677669529663687f;         // 1/(sqrt(2)*4)

    __shared__ float xs[ROWS_PER_BLOCK * ROW_STRIDE];  // 4352 B

    const int t  = threadIdx.x;
    const int sc = blockIdx.x;

    for (int rep = 0; rep < 2; ++rep) {
        __syncthreads();                               // WAR guard between reps

        // stage 64 rows (4 KB) — each thread loads one float4 -> stride-17 rows
        {
            const fvec4* x4 = reinterpret_cast<const fvec4*>(x) + (size_t)sc * X_VEC4;
            fvec4 v = x4[t];
            const int row = t >> 2;
            const int col = (t & 3) * 4;
            float* dst = &xs[row * ROW_STRIDE + col];
            dst[0] = v[0]; dst[1] = v[1]; dst[2] = v[2]; dst[3] = v[3];
            if (t < ROWS_PER_BLOCK) xs[t * ROW_STRIDE + FDIM] = 1.0f;
        }
        __syncthreads();

        fvec4* out4 = reinterpret_cast<fvec4*>(out) + (size_t)sc * SUPER_VEC4;

#pragma unroll 2
        for (int p = 0; p < 18; ++p) {
            const int q = p * 256 + t;
            if (q < SUPER_VEC4) {
                const int f0 = q * 4;
                fvec4 v;
#pragma unroll
                for (int e = 0; e < 4; ++e) {
                    const int f  = f0 + e;
                    const int r  = f / OUT_PER_ROW;    // 0..63 (magic-mul)
                    const int k  = f - r * OUT_PER_ROW;
                    const int kk = k - (FDIM + 1);
                    const bool isq = kk >= 0;
                    const int iA = isq ? (kk >> 4) : (k > 0 ? k - 1 : FDIM);
                    const int iB = isq ? (kk & 15) : FDIM;
                    const float S = isq ? C2 : (k > 0 ? 0.5f : 1.0f);
                    const float* xr = &xs[r * ROW_STRIDE];
                    v[e] = xr[iA] * xr[iB] * S;
                }
                out4[q] = v;
            }
        }

        // keep both reps' stores (block dead-store elimination across reps)
        asm volatile("" ::: "memory");
    }
}

extern "C" void kernel_launch(void* const* d_in, const int* in_sizes, int n_in,
                              void* d_out, int out_size, void* d_ws, size_t ws_size,
                              hipStream_t stream) {
    const float* x = (const float*)d_in[0];
    float* out = (float*)d_out;

    const int total_x = in_sizes[0];                   // B*H*S*16
    const int nrows   = total_x / FDIM;                // 262144
    const int nsuper  = nrows / ROWS_PER_BLOCK;        // 4096

    based_feature_kernel<<<dim3(nsuper), dim3(256), 0, stream>>>(x, out);
}